// Round 7
// baseline (29.915 us; speedup 1.0000x reference)
//
#include <hip/hip_runtime.h>
#include <hip/hip_fp16.h>
#include <math.h>

#define D 64
#define NS 64      // S: tokens per shard
#define H 8
#define NSHARD 128 // B * n_shards
#define NBLK_B (NSHARD * 16)   // 2048 blocks, 1 k-col per wave
#define TBL 512    // LUT entries over [-8, 8), nearest-neighbor (centers baked)
constexpr float LR = 0.01f;
constexpr float WD = 0.01f;
constexpr float GSCALE = (float)TBL / 16.0f;   // 32 entries per unit g
constexpr float GOFF   = 8.0f * GSCALE;        // 256
constexpr float TMAXN  = 511.0f;               // clamp for nearest index

typedef __attribute__((ext_vector_type(8))) short bf16x8;  // 8 bf16 (4 VGPR)
typedef __attribute__((ext_vector_type(4))) float f32x4;

__device__ __forceinline__ short f2bf(float f) {           // f32 -> bf16 RNE
    unsigned u = __float_as_uint(f);
    return (short)((u + 0x7FFF + ((u >> 16) & 1)) >> 16);
}

template<int CTRL, int RM>
__device__ __forceinline__ float dpp_add(float v) {
    int t = __builtin_amdgcn_update_dpp(0, __float_as_int(v), CTRL, RM, 0xf, true);
    return v + __int_as_float(t);
}

// ---------------- kernel A: per-shard prep (1 block per shard) ----------------
// Writes to workspace:
//   xq_ws[n][j*64 + s]  u32 half2(x,q)   (2 MB)  -- [j][s] layout for B's reads
//   e_ws [n][s*64 + k]  f32 E*GSCALE     (2 MB)
//   tl_ws[512]          f32 LUT          (2 KB)  -- block 0 only
__global__ __launch_bounds__(256, 4) void tnt_prep(const float* __restrict__ X,
                                                   const float* __restrict__ mem0,
                                                   const float* __restrict__ opt,
                                                   const float* __restrict__ Wq,
                                                   unsigned* __restrict__ xq_ws,
                                                   float* __restrict__ e_ws,
                                                   float* __restrict__ tl_ws) {
    __shared__ __align__(16) short WT[2 * 64 * 72];   // W0^T | Wq^T bf16 staging
    const int n    = blockIdx.x;                      // shard; XCD = n % 8
    const int tid  = threadIdx.x;
    const int wv   = tid >> 6;
    const int lane = tid & 63;
    const int l15  = lane & 15, lhi = lane >> 4;
    const float* Xs = X + n * NS * D;

    // stage W0^T and Wq^T bf16 in one pass
    {
        const int m     = tid >> 7;            // matrix 0/1
        const int kcol  = tid & 63;            // output column of W
        const int gbase = ((tid >> 6) & 1) * 4;
        const float* Wm = m ? Wq : mem0;
#pragma unroll
        for (int gg = 0; gg < 4; ++gg) {
            const int g = gbase + gg;
            bf16x8 pk;
#pragma unroll
            for (int i = 0; i < 8; ++i)
                pk[i] = f2bf(Wm[(g * 8 + i) * D + kcol]);   // coalesced per i
            *(bf16x8*)(WT + (m * 64 + kcol) * 72 + g * 8) = pk;
        }
    }
    // A-frags (rows wv*16 + l15), shared by both GEMMs
    bf16x8 afrag[2];
    {
        const float* xrow = Xs + (wv * 16 + l15) * D + lhi * 8;
#pragma unroll
        for (int ks = 0; ks < 2; ++ks) {
            const float4 u0 = *(const float4*)(xrow + ks * 32);
            const float4 u1 = *(const float4*)(xrow + ks * 32 + 4);
            bf16x8 a;
            a[0]=f2bf(u0.x); a[1]=f2bf(u0.y); a[2]=f2bf(u0.z); a[3]=f2bf(u0.w);
            a[4]=f2bf(u1.x); a[5]=f2bf(u1.y); a[6]=f2bf(u1.z); a[7]=f2bf(u1.w);
            afrag[ks] = a;
        }
    }
    __syncthreads();

    // both GEMMs
    f32x4 accE[4], accQ[4];
#pragma unroll
    for (int nt = 0; nt < 4; ++nt) { accE[nt] = 0; accQ[nt] = 0; }
#pragma unroll
    for (int nt = 0; nt < 4; ++nt) {
        const int col = nt * 16 + l15;
#pragma unroll
        for (int ks = 0; ks < 2; ++ks) {
            const bf16x8 b0 = *(const bf16x8*)(WT + col * 72 + ks * 32 + lhi * 8);
            const bf16x8 b1 = *(const bf16x8*)(WT + (64 + col) * 72 + ks * 32 + lhi * 8);
            accE[nt] = __builtin_amdgcn_mfma_f32_16x16x32_bf16(afrag[ks], b0, accE[nt], 0,0,0);
            accQ[nt] = __builtin_amdgcn_mfma_f32_16x16x32_bf16(afrag[ks], b1, accQ[nt], 0,0,0);
        }
    }
    // fused epilogue: one X load feeds both E and XQ outputs
    const float c = (2.0f / (float)D) * GSCALE;
    const int erow = wv * 16 + lhi * 4;
    unsigned* xqn = xq_ws + n * 4096;
    float*    en  = e_ws  + n * 4096;
#pragma unroll
    for (int nt = 0; nt < 4; ++nt) {
#pragma unroll
        for (int r = 0; r < 4; ++r) {
            const int row = erow + r;                   // s
            const int col = nt * 16 + l15;              // j / k
            const float xv = Xs[row * D + col];
            en[row * 64 + col] = c * (accE[nt][r] - xv);           // coalesced
            const __half2 h = __halves2half2(__float2half_rn(xv),
                                             __float2half_rn(accQ[nt][r]));
            xqn[col * 64 + row] = *(const unsigned*)&h;            // scattered, L2
        }
    }
    // LUT (block 0 only): LR-scaled nearest, cell centers
    if (n == 0) {
        float w1d[H], b1d[H], w2[H];
#pragma unroll
        for (int h = 0; h < H; ++h) {
            w1d[h] = 2.0f * opt[h]; b1d[h] = 2.0f * opt[H + h]; w2[h] = opt[2 * H + h];
        }
        const float b2 = opt[3 * H];
#pragma unroll
        for (int jj = tid; jj < TBL; jj += 256) {      // 2 iterations
            const float g = ((float)jj + 0.5f - GOFF) / GSCALE;
            float acc = b2;
#pragma unroll
            for (int h = 0; h < H; ++h) {
                const float u = __expf(fmaf(w1d[h], g, b1d[h]));   // e^{2y}
                acc = fmaf(w2[h], (u - 1.0f) * __builtin_amdgcn_rcpf(u + 1.0f), acc);
            }
            tl_ws[jj] = LR * acc;
        }
    }
}

// ---------------- kernel B: main loop (prep-free, 8 blocks/CU) ----------------
__global__ __launch_bounds__(256, 8) void tnt_main(const unsigned* __restrict__ xq_ws,
                                                   const float* __restrict__ e_ws,
                                                   const float* __restrict__ tl_ws,
                                                   const float* __restrict__ mem0,
                                                   float* __restrict__ out) {
    __shared__ float Tl[TBL];                  // only LDS use: 2048 B
    const int bid  = (int)blockIdx.x;
    const int xcd  = bid & 7;
    const int idx  = bid >> 3;
    const int n    = (idx >> 4) * 8 + xcd;     // shard n on XCD n%8 == producer's
    const int kq   = idx & 15;
    const int tid  = threadIdx.x;
    const int wv   = tid >> 6;
    const int lane = tid & 63;
    const int k0   = (kq << 2) + wv;           // this wave's k column

    Tl[tid]       = tl_ws[tid];
    Tl[tid + 256] = tl_ws[tid + 256];
    const float m0v  = mem0[lane * D + k0];
    const float wdm0 = WD * m0v;
    const float e0   = e_ws[n * 4096 + lane * 64 + k0];  // E[s=lane][k0]*GSCALE
    __syncthreads();

    const unsigned* xrow = xq_ws + n * 4096 + lane * 64; // this lane's j-column
    float cum = m0v;
    const int  bp32 = ((lane ^ 32) << 2);      // ds_bpermute byte index for xor32
    const bool s1 = (lane & 1) != 0;
    const bool s2 = (lane & 2) != 0;
    const bool s4 = (lane & 4) != 0;
    float* orow = out + n * NS * D + k0;

#pragma unroll
    for (int b = 0; b < 8; ++b) {
        const uint4 xa = *(const uint4*)(xrow + b * 8);      // L2-hot, 16B/lane
        const uint4 xb = *(const uint4*)(xrow + b * 8 + 4);
        const unsigned xw[8] = {xa.x, xa.y, xa.z, xa.w, xb.x, xb.y, xb.z, xb.w};
        float q8[8], v8[8];
#pragma unroll
        for (int u = 0; u < 8; ++u) {          // independent across u
            const int s = (b << 3) + u;
            const float ek = __int_as_float(
                __builtin_amdgcn_readlane(__float_as_int(e0), s));
            const __half2 hv = *(const __half2*)&xw[u];
            const float xv = __low2float(hv);
            q8[u] = __high2float(hv);
            const float t = __builtin_amdgcn_fmed3f(fmaf(xv, ek, GOFF), 0.0f, TMAXN);
            v8[u] = Tl[(int)t] + wdm0;         // single b32 gather per u
        }
        float p8[8];
#pragma unroll
        for (int u = 0; u < 8; ++u) {          // serial cum chain + row-16 DPP reduce
            cum -= v8[u];
            float p = q8[u] * cum;
            p = dpp_add<0xB1,  0xf>(p);        // xor 1
            p = dpp_add<0x4E,  0xf>(p);        // xor 2
            p = dpp_add<0x141, 0xf>(p);        // row_half_mirror -> 8-sum
            p = dpp_add<0x140, 0xf>(p);        // row_mirror      -> 16-sum
            p8[u] = p;
        }
        // per-lane select: lane picks u = lane&7 (7 cndmask, static idx)
        const float t0 = s1 ? p8[1] : p8[0];
        const float t1 = s1 ? p8[3] : p8[2];
        const float t2 = s1 ? p8[5] : p8[4];
        const float t3 = s1 ? p8[7] : p8[6];
        const float a0 = s2 ? t1 : t0;
        const float a1 = s2 ? t3 : t2;
        float val = s4 ? a1 : a0;
        // cross-row sum: xor16 (ds_swizzle) + xor32 (ds_bpermute)
        val += __int_as_float(__builtin_amdgcn_ds_swizzle(__float_as_int(val), 0x401F));
        val += __int_as_float(__builtin_amdgcn_ds_bpermute(bp32, __float_as_int(val)));
        if (lane < 8)                          // lanes 0..7 hold full sums for u=lane
            orow[((b << 3) + lane) * D] = val;
    }
}

extern "C" void kernel_launch(void* const* d_in, const int* in_sizes, int n_in,
                              void* d_out, int out_size, void* d_ws, size_t ws_size,
                              hipStream_t stream) {
    const float* X    = (const float*)d_in[0];   // (4,2048,64)
    const float* mem0 = (const float*)d_in[1];   // (4096,)
    const float* opt  = (const float*)d_in[2];   // (25,)
    const float* Wq   = (const float*)d_in[3];   // (64,64)
    float* out = (float*)d_out;

    // workspace carve: 2 MB xq | 2 MB e | 2 KB lut   (total 4,196,352 B)
    unsigned* xq_ws = (unsigned*)d_ws;
    float*    e_ws  = (float*)((char*)d_ws + 2097152);
    float*    tl_ws = (float*)((char*)d_ws + 4194304);

    tnt_prep<<<dim3(NSHARD), dim3(256), 0, stream>>>(X, mem0, opt, Wq, xq_ws, e_ws, tl_ws);
    tnt_main<<<dim3(NBLK_B), dim3(256), 0, stream>>>(xq_ws, e_ws, tl_ws, mem0, out);
}

// Round 8
// 21.260 us; speedup vs baseline: 1.4071x; 1.4071x over previous
//
#include <hip/hip_runtime.h>
#include <hip/hip_fp16.h>
#include <math.h>

#define D 64
#define NS 64      // S: tokens per shard
#define H 8
#define NSHARD 128 // B * n_shards
#define KPB 16     // k columns per block (2 per wave, 8 waves)
#define NBLK (NSHARD * (D / KPB))   // 512 blocks = 2/CU exactly
#define NTHR 512
#define TBL 512    // LUT entries over [-8, 8), nearest-neighbor (centers baked)
constexpr float LR = 0.01f;
constexpr float WD = 0.01f;
constexpr float GSCALE = (float)TBL / 16.0f;   // 32 entries per unit g
constexpr float GOFF   = 8.0f * GSCALE;        // 256
constexpr float TMAXN  = 511.0f;               // clamp for nearest index

typedef __attribute__((ext_vector_type(8))) short bf16x8;  // 8 bf16 (4 VGPR)
typedef __attribute__((ext_vector_type(4))) float f32x4;
typedef __attribute__((ext_vector_type(2))) float f32x2;   // -> v_pk_*_f32

__device__ __forceinline__ short f2bf(float f) {           // f32 -> bf16 RNE
    unsigned u = __float_as_uint(f);
    return (short)((u + 0x7FFF + ((u >> 16) & 1)) >> 16);
}

template<int CTRL, int RM>
__device__ __forceinline__ float dpp_add(float v) {
    int t = __builtin_amdgcn_update_dpp(0, __float_as_int(v), CTRL, RM, 0xf, true);
    return v + __int_as_float(t);
}

// LDS layout (54144 B, 2 blocks/CU; NO overlays -- every region lives alone):
//   [0,    11520): WT[80][72] bf16 -- rows 0-15: W0^T E-tile cols (this block's 16),
//                                    rows 16-79: Wq^T all 64 cols
//   [11520,28928): XQT[64 j][68 s] u32 (half2(x,q))
//   [28928,33536): Esm[64 s][18] f32 (cols 0-15 = this block's E cols, GSCALE-baked)
//   [33536,35584): Tl[512] f32 (nearest LUT, cell centers)
//   [35584,54144): o4[4][1160] f32 -- 4 row-copies x 64 s x 18 (16 k-cols + pad)
#define OFF_XQT  11520
#define OFF_ESM  28928
#define OFF_TL   33536
#define OFF_O4   35584
#define SM_BYTES 54144
#define O4_R     1160
#define O4_S     18

__global__ __launch_bounds__(NTHR, 4) void tnt_fused(const float* __restrict__ X,
                                                     const float* __restrict__ mem0,
                                                     const float* __restrict__ opt,
                                                     const float* __restrict__ Wq,
                                                     float* __restrict__ out) {
    __shared__ __align__(16) char smem[SM_BYTES];
    short*    WT   = (short*)(smem);
    unsigned* XQT  = (unsigned*)(smem + OFF_XQT);
    float*    EsmF = (float*)(smem + OFF_ESM);
    float*    Tl   = (float*)(smem + OFF_TL);
    float*    o4   = (float*)(smem + OFF_O4);

    // XCD swizzle: the 4 blocks of a shard land on one XCD's L2 (512 % 8 == 0)
    const int bid  = ((int)blockIdx.x & 7) * (NBLK / 8) + ((int)blockIdx.x >> 3);
    const int n    = bid >> 2;
    const int kq   = bid & 3;
    const int tid  = threadIdx.x;
    const int wv   = tid >> 6;            // 0..7
    const int lane = tid & 63;
    const int rg   = wv & 3;              // GEMM row-group (16 rows each)
    const int l15  = lane & 15, lhi = lane >> 4;
    const int k0   = (kq << 4) + (wv << 1);   // this wave's first k column

    const float* Xs = X + n * NS * D;

    // ---- phase 1: stage W0^T E-tile (16 cols) + Wq^T (64 cols) ----
    // 640 bf16x8 packs over 512 threads (threads 0-127 do two)
    for (int t = tid; t < 640; t += NTHR) {
        const int  isq    = t >= 128;
        const int  tt     = isq ? t - 128 : t;
        const int  colsrc = isq ? (tt & 63) : ((kq << 4) + (tt & 15));
        const int  rowdst = isq ? (16 + (tt & 63)) : (tt & 15);
        const int  g      = isq ? (tt >> 6) : (tt >> 4);
        const float* Wm   = isq ? Wq : mem0;
        bf16x8 pk;
#pragma unroll
        for (int i = 0; i < 8; ++i)
            pk[i] = f2bf(Wm[(g * 8 + i) * D + colsrc]);   // coalesced per i
        *(bf16x8*)(WT + rowdst * 72 + g * 8) = pk;
    }
    // A-frags (rows rg*16 + l15), used by this wave's GEMM half
    bf16x8 afrag[2];
    {
        const float* xrow = Xs + (rg * 16 + l15) * D + lhi * 8;
#pragma unroll
        for (int ks = 0; ks < 2; ++ks) {
            const float4 u0 = *(const float4*)(xrow + ks * 32);
            const float4 u1 = *(const float4*)(xrow + ks * 32 + 4);
            bf16x8 a;
            a[0]=f2bf(u0.x); a[1]=f2bf(u0.y); a[2]=f2bf(u0.z); a[3]=f2bf(u0.w);
            a[4]=f2bf(u1.x); a[5]=f2bf(u1.y); a[6]=f2bf(u1.z); a[7]=f2bf(u1.w);
            afrag[ks] = a;
        }
    }
    const float2 m0v = *(const float2*)(mem0 + lane * D + k0);  // both k-cols
    const f32x2 wdm2 = {WD * m0v.x, WD * m0v.y};
    __syncthreads();

    // ---- phase 2 (split): waves 0-3 Q GEMM + XQT; waves 4-7 E tile + LUT ----
    if (wv < 4) {
        f32x4 accQ[4];
#pragma unroll
        for (int nt = 0; nt < 4; ++nt) accQ[nt] = 0;
#pragma unroll
        for (int nt = 0; nt < 4; ++nt) {
            const int col = nt * 16 + l15;
#pragma unroll
            for (int ks = 0; ks < 2; ++ks) {
                const bf16x8 b1 = *(const bf16x8*)(WT + (16 + col) * 72 + ks * 32 + lhi * 8);
                accQ[nt] = __builtin_amdgcn_mfma_f32_16x16x32_bf16(afrag[ks], b1, accQ[nt], 0,0,0);
            }
        }
        // XQT epilogue: half2(x, q), row=j(col), col=s layout
#pragma unroll
        for (int nt = 0; nt < 4; ++nt) {
#pragma unroll
            for (int r = 0; r < 4; ++r) {
                const int row = rg * 16 + lhi * 4 + r;      // s
                const int col = nt * 16 + l15;              // j
                const __half2 h = __halves2half2(__float2half_rn(Xs[row * D + col]),
                                                 __float2half_rn(accQ[nt][r]));
                XQT[col * 68 + row] = *(const unsigned*)&h;
            }
        }
    } else {
        f32x4 accE = 0;
#pragma unroll
        for (int ks = 0; ks < 2; ++ks) {
            const bf16x8 b0 = *(const bf16x8*)(WT + l15 * 72 + ks * 32 + lhi * 8);
            accE = __builtin_amdgcn_mfma_f32_16x16x32_bf16(afrag[ks], b0, accE, 0,0,0);
        }
        const float c = (2.0f / (float)D) * GSCALE;
        const int ecol = (kq << 4) + l15;
#pragma unroll
        for (int r = 0; r < 4; ++r) {
            const int row = rg * 16 + lhi * 4 + r;
            EsmF[row * O4_S + l15] = c * (accE[r] - Xs[row * D + ecol]);
        }
        // LR-scaled nearest LUT (256 threads, 2 entries each)
        float w1d[H], b1d[H], w2[H];
#pragma unroll
        for (int h = 0; h < H; ++h) {
            w1d[h] = 2.0f * opt[h]; b1d[h] = 2.0f * opt[H + h]; w2[h] = opt[2 * H + h];
        }
        const float b2 = opt[3 * H];
        const int base = tid - 256;            // 0..255
#pragma unroll
        for (int jj = base; jj < TBL; jj += 256) {
            const float g = ((float)jj + 0.5f - GOFF) / GSCALE;
            float acc = b2;
#pragma unroll
            for (int h = 0; h < H; ++h) {
                const float u = __expf(fmaf(w1d[h], g, b1d[h]));   // e^{2y}
                acc = fmaf(w2[h], (u - 1.0f) * __builtin_amdgcn_rcpf(u + 1.0f), acc);
            }
            Tl[jj] = LR * acc;
        }
    }
    __syncthreads();   // XQT + Esm + Tl ready

    const float2 ee = *(const float2*)(EsmF + lane * O4_S + (wv << 1));
    const float e0 = ee.x;     // E[n, s=lane, k0]   * GSCALE
    const float e1 = ee.y;     // E[n, s=lane, k0+1] * GSCALE

    // ---- main loop: R4 structure, 8 fully-unrolled batches, 1 ds_write/batch ----
    const unsigned* xrow = XQT + lane * 68;    // this lane's j-column, along s
    f32x2 cum = {m0v.x, m0v.y};

    // lane -> (row-copy r, step u, col k) for the partial write
    const int r4  = lane >> 4;
    const int w16 = lane & 15;
    const bool selk  = (w16 & 1) != 0;
    const bool selu0 = (w16 & 2) != 0;
    const bool selu1 = (w16 & 4) != 0;
    const bool selu2 = (w16 & 8) != 0;
    float* wbase = o4 + r4 * O4_R + (w16 >> 1) * O4_S + (wv << 1) + (w16 & 1);

#pragma unroll
    for (int b = 0; b < 8; ++b) {
        const uint4 xa = *(const uint4*)(xrow + b * 8);
        const uint4 xb = *(const uint4*)(xrow + b * 8 + 4);
        const unsigned xw[8] = {xa.x, xa.y, xa.z, xa.w, xb.x, xb.y, xb.z, xb.w};
        float q8[8];
        f32x2 v01[8];
#pragma unroll
        for (int u = 0; u < 8; ++u) {          // independent across u AND k
            const int s = (b << 3) + u;
            const float ek0 = __int_as_float(
                __builtin_amdgcn_readlane(__float_as_int(e0), s));
            const float ek1 = __int_as_float(
                __builtin_amdgcn_readlane(__float_as_int(e1), s));
            const __half2 hv = *(const __half2*)&xw[u];
            const float xv = __low2float(hv);
            q8[u] = __high2float(hv);
            const float t0 = __builtin_amdgcn_fmed3f(fmaf(xv, ek0, GOFF), 0.0f, TMAXN);
            const float t1 = __builtin_amdgcn_fmed3f(fmaf(xv, ek1, GOFF), 0.0f, TMAXN);
            f32x2 g2; g2.x = Tl[(int)t0]; g2.y = Tl[(int)t1];   // b32 gathers
            v01[u] = g2 + wdm2;                // v_pk_add_f32
        }
        float p0s[8], p1s[8];
#pragma unroll
        for (int u = 0; u < 8; ++u) {          // chain + full-row DPP reduce
            cum = cum - v01[u];                // v_pk_add_f32 (neg)
            f32x2 qq; qq.x = q8[u]; qq.y = q8[u];
            const f32x2 p = qq * cum;          // v_pk_mul_f32
            float x0 = dpp_add<0xB1,  0xf>(p.x);   // xor 1
            x0       = dpp_add<0x4E,  0xf>(x0);    // xor 2
            x0       = dpp_add<0x141, 0xf>(x0);    // row_half_mirror -> 8-sum
            x0       = dpp_add<0x140, 0xf>(x0);    // row_mirror      -> 16-sum
            float x1 = dpp_add<0xB1,  0xf>(p.y);
            x1       = dpp_add<0x4E,  0xf>(x1);
            x1       = dpp_add<0x141, 0xf>(x1);
            x1       = dpp_add<0x140, 0xf>(x1);
            p0s[u] = x0; p1s[u] = x1;
        }
        // per-lane select of its (u,k) 16-row partial (15 cndmask, static idx)
        const float t0_ = selk ? p1s[0] : p0s[0];
        const float t1_ = selk ? p1s[1] : p0s[1];
        const float t2_ = selk ? p1s[2] : p0s[2];
        const float t3_ = selk ? p1s[3] : p0s[3];
        const float t4_ = selk ? p1s[4] : p0s[4];
        const float t5_ = selk ? p1s[5] : p0s[5];
        const float t6_ = selk ? p1s[6] : p0s[6];
        const float t7_ = selk ? p1s[7] : p0s[7];
        const float a0 = selu0 ? t1_ : t0_;
        const float a1 = selu0 ? t3_ : t2_;
        const float a2 = selu0 ? t5_ : t4_;
        const float a3 = selu0 ? t7_ : t6_;
        const float b0 = selu1 ? a1 : a0;
        const float b1 = selu1 ? a3 : a2;
        const float val = selu2 ? b1 : b0;
        wbase[b * (8 * O4_S)] = val;           // ds_write_b32, imm offset 576*b
    }

    __syncthreads();
    // epilogue: sum the 4 row-copies; 2 floats per thread (b64 reads/store)
    const int s_ = tid >> 3;                   // 0..63
    const int c2 = (tid & 7) << 1;             // 0,2,..,14
    float ox = 0.0f, oy = 0.0f;
#pragma unroll
    for (int r = 0; r < 4; ++r) {
        const float2 v = *(const float2*)(o4 + r * O4_R + s_ * O4_S + c2);
        ox += v.x; oy += v.y;
    }
    *(float2*)(out + (n * NS + s_) * D + (kq << 4) + c2) = make_float2(ox, oy);
}

extern "C" void kernel_launch(void* const* d_in, const int* in_sizes, int n_in,
                              void* d_out, int out_size, void* d_ws, size_t ws_size,
                              hipStream_t stream) {
    const float* X    = (const float*)d_in[0];   // (4,2048,64)
    const float* mem0 = (const float*)d_in[1];   // (4096,)
    const float* opt  = (const float*)d_in[2];   // (25,)
    const float* Wq   = (const float*)d_in[3];   // (64,64)
    float* out = (float*)d_out;

    tnt_fused<<<dim3(NBLK), dim3(NTHR), 0, stream>>>(X, mem0, opt, Wq, out);
}